// Round 11
// baseline (1713.915 us; speedup 1.0000x reference)
//
#include <hip/hip_runtime.h>
#include <hip/hip_bf16.h>

#define NN 100000
#define NE 250000
#define DD 300
#define DDB 304       // bf16 h row stride
#define NL 5
#define MPAD 100096   // 782*128
#define KA1 320       // padded K for GEMM1
#define N1 608        // m1 width (600+8 pad), K of GEMM2
#define N1T 640       // W1T rows (5 col-blocks * 128)
#define K2 608
#define N2T 384       // W2T rows (300->384)
#define NBLK 391
#define NCMB 19

typedef __attribute__((ext_vector_type(8))) short short8;
typedef __attribute__((ext_vector_type(4))) float f32x4;

#define GLBP(x) ((const __attribute__((address_space(1))) unsigned int*)(x))
#define LDSP(x) ((__attribute__((address_space(3))) unsigned int*)(x))
#define WAITV(N) asm volatile("s_waitcnt vmcnt(" #N ")" ::: "memory")

__device__ __forceinline__ ushort f2bf(float f){
  unsigned u = __float_as_uint(f);
  u += 0x7FFFu + ((u >> 16) & 1u);
  return (ushort)(u >> 16);
}
__device__ __forceinline__ float bf2f(ushort h){
  return __uint_as_float((unsigned)h << 16);
}
__device__ __forceinline__ unsigned pk2(float a, float b){
  return (unsigned)f2bf(a) | ((unsigned)f2bf(b) << 16);
}

// ---------------- weight prep: transpose + f32->bf16, zero-padded ----------
__global__ void prep_weights(const float* __restrict__ W1, const float* __restrict__ W2,
                             ushort* __restrict__ W1T, ushort* __restrict__ W2T){
  int idx = blockIdx.x * 256 + threadIdx.x;
  const int total1 = NL * N1T * KA1;
  const int total2 = NL * N2T * K2;
  if (idx < total1){
    int l = idx / (N1T * KA1);
    int rem = idx % (N1T * KA1);
    int n = rem / KA1, k = rem % KA1;
    float v = (n < 2*DD && k < DD) ? W1[(size_t)l*DD*2*DD + (size_t)k*2*DD + n] : 0.0f;
    W1T[idx] = f2bf(v);
  } else {
    int idx2 = idx - total1;
    if (idx2 < total2){
      int l = idx2 / (N2T * K2);
      int rem = idx2 % (N2T * K2);
      int n = rem / K2, k = rem % K2;
      float v = (n < DD && k < 2*DD) ? W2[(size_t)l*2*DD*DD + (size_t)k*DD + n] : 0.0f;
      W2T[idx2] = f2bf(v);
    }
  }
}

// -------- combo tables ----------
__global__ void prep_ctab(const float* __restrict__ E1, const float* __restrict__ E2,
                          float* __restrict__ ctab){
  int idx = blockIdx.x * 256 + threadIdx.x;
  if (idx >= NL * NCMB * DDB) return;
  int l = idx / (NCMB * DDB);
  int rem = idx % (NCMB * DDB);
  int c = rem / DDB, d = rem % DDB;
  float v = 0.0f;
  if (d < DD){
    int bt = (c < 18) ? (c / 3) : 4;
    int bd = (c < 18) ? (c % 3) : 0;
    v = E1[(size_t)l*6*DD + bt*DD + d] + E2[(size_t)l*3*DD + bd*DD + d];
  }
  ctab[idx] = v;
}

// ---------------- CSR build ------------------------------------------------
__global__ void csr_count(const int* __restrict__ ei, int* __restrict__ deg){
  int e = blockIdx.x * 256 + threadIdx.x;
  if (e < NE) atomicAdd(&deg[ei[NE + e]], 1);
}

__global__ void scan_blk(const int* __restrict__ deg, int* __restrict__ rs, int* __restrict__ bsum){
  __shared__ int tmp[256];
  int i = blockIdx.x * 256 + threadIdx.x;
  int v = (i < NN) ? deg[i] : 0;
  tmp[threadIdx.x] = v;
  __syncthreads();
  #pragma unroll
  for (int off = 1; off < 256; off <<= 1){
    int t = (threadIdx.x >= off) ? tmp[threadIdx.x - off] : 0;
    __syncthreads();
    tmp[threadIdx.x] += t;
    __syncthreads();
  }
  if (i < NN) rs[i] = tmp[threadIdx.x] - v;
  if (threadIdx.x == 255) bsum[blockIdx.x] = tmp[255];
}

__global__ void scan_top(int* __restrict__ bsum){
  __shared__ int tmp[512];
  int v = (threadIdx.x < NBLK) ? bsum[threadIdx.x] : 0;
  tmp[threadIdx.x] = v;
  __syncthreads();
  #pragma unroll
  for (int off = 1; off < 512; off <<= 1){
    int t = (threadIdx.x >= off) ? tmp[threadIdx.x - off] : 0;
    __syncthreads();
    tmp[threadIdx.x] += t;
    __syncthreads();
  }
  if (threadIdx.x < NBLK) bsum[threadIdx.x] = tmp[threadIdx.x] - v;
}

__global__ void scan_add(int* __restrict__ rs, const int* __restrict__ bsum){
  int i = blockIdx.x * 256 + threadIdx.x;
  if (i < NN) rs[i] += bsum[blockIdx.x];
  if (i == 0) rs[NN] = NE;
}

__global__ void csr_fill(const int* __restrict__ ei, const int* __restrict__ ea,
                         const int* __restrict__ rs, int* __restrict__ cursor,
                         int* __restrict__ edges){
  int e = blockIdx.x * 256 + threadIdx.x;
  if (e < NE){
    int dst = ei[NE + e];
    int src = ei[e];
    int c = ea[2*e] * 3 + ea[2*e + 1];
    int p = rs[dst] + atomicAdd(&cursor[dst], 1);
    edges[p] = src | (c << 20);
  }
}

// ---- gather: wave-per-row, grid-stride (r6/r8-proven) ----
template<int HBF>
__global__ __launch_bounds__(256) void gather_agg(
    const void* __restrict__ hp, const float2* __restrict__ ss,
    const float* __restrict__ ctab_l,
    const int* __restrict__ rs, const int* __restrict__ edges,
    ushort* __restrict__ agg)
{
  int lane = threadIdx.x & 63;
  int wq = __builtin_amdgcn_readfirstlane(threadIdx.x >> 6);
  int wid = blockIdx.x * 4 + wq;
  int nw = gridDim.x * 4;
  int dA = lane * 4;
  int dB = 256 + lane * 4;
  bool laneB  = (lane < 16);
  bool validB = (dB < DD);

  float scA[4], shA[4], scB[4], shB[4];
  if (HBF){
    #pragma unroll
    for (int j = 0; j < 4; ++j){
      float2 s = ss[dA + j]; scA[j] = s.x; shA[j] = s.y;
    }
    if (validB){
      #pragma unroll
      for (int j = 0; j < 4; ++j){
        float2 s = ss[dB + j]; scB[j] = s.x; shB[j] = s.y;
      }
    }
  }

  const float*  hf = (const float*)hp;
  const ushort* hb = (const ushort*)hp;
  const float* ctS = ctab_l + 18*DDB;

  for (int row = wid; row < MPAD; row += nw){
    float a0=0,a1=0,a2=0,a3=0, b0=0,b1v=0,b2v=0,b3=0;
    if (row < NN){
      if (HBF){
        uint2 hw = *(const uint2*)(hb + (size_t)row*DDB + dA);
        a0 = fmaxf(bf2f((ushort)hw.x)*scA[0]+shA[0],0.f)      + ctS[dA+0];
        a1 = fmaxf(bf2f((ushort)(hw.x>>16))*scA[1]+shA[1],0.f)+ ctS[dA+1];
        a2 = fmaxf(bf2f((ushort)hw.y)*scA[2]+shA[2],0.f)      + ctS[dA+2];
        a3 = fmaxf(bf2f((ushort)(hw.y>>16))*scA[3]+shA[3],0.f)+ ctS[dA+3];
        if (validB){
          uint2 hv = *(const uint2*)(hb + (size_t)row*DDB + dB);
          b0  = fmaxf(bf2f((ushort)hv.x)*scB[0]+shB[0],0.f)      + ctS[dB+0];
          b1v = fmaxf(bf2f((ushort)(hv.x>>16))*scB[1]+shB[1],0.f)+ ctS[dB+1];
          b2v = fmaxf(bf2f((ushort)hv.y)*scB[2]+shB[2],0.f)      + ctS[dB+2];
          b3  = fmaxf(bf2f((ushort)(hv.y>>16))*scB[3]+shB[3],0.f)+ ctS[dB+3];
        }
      } else {
        float4 hv = *(const float4*)(hf + (size_t)row*DD + dA);
        a0 = hv.x + ctS[dA+0]; a1 = hv.y + ctS[dA+1];
        a2 = hv.z + ctS[dA+2]; a3 = hv.w + ctS[dA+3];
        if (validB){
          float4 hv2 = *(const float4*)(hf + (size_t)row*DD + dB);
          b0 = hv2.x + ctS[dB+0]; b1v = hv2.y + ctS[dB+1];
          b2v = hv2.z + ctS[dB+2]; b3 = hv2.w + ctS[dB+3];
        }
      }
      int p = rs[row], pe = rs[row + 1];
      for (; p < pe; ++p){
        int ew = edges[p];
        int src = ew & 0xFFFFF;
        const float* ct = ctab_l + (ew >> 20)*DDB;
        if (HBF){
          uint2 hw = *(const uint2*)(hb + (size_t)src*DDB + dA);
          a0 += fmaxf(bf2f((ushort)hw.x)*scA[0]+shA[0],0.f)      + ct[dA+0];
          a1 += fmaxf(bf2f((ushort)(hw.x>>16))*scA[1]+shA[1],0.f)+ ct[dA+1];
          a2 += fmaxf(bf2f((ushort)hw.y)*scA[2]+shA[2],0.f)      + ct[dA+2];
          a3 += fmaxf(bf2f((ushort)(hw.y>>16))*scA[3]+shA[3],0.f)+ ct[dA+3];
          if (validB){
            uint2 hv = *(const uint2*)(hb + (size_t)src*DDB + dB);
            b0  += fmaxf(bf2f((ushort)hv.x)*scB[0]+shB[0],0.f)      + ct[dB+0];
            b1v += fmaxf(bf2f((ushort)(hv.x>>16))*scB[1]+shB[1],0.f)+ ct[dB+1];
            b2v += fmaxf(bf2f((ushort)hv.y)*scB[2]+shB[2],0.f)      + ct[dB+2];
            b3  += fmaxf(bf2f((ushort)(hv.y>>16))*scB[3]+shB[3],0.f)+ ct[dB+3];
          }
        } else {
          float4 hv = *(const float4*)(hf + (size_t)src*DD + dA);
          a0 += hv.x + ct[dA+0]; a1 += hv.y + ct[dA+1];
          a2 += hv.z + ct[dA+2]; a3 += hv.w + ct[dA+3];
          if (validB){
            float4 hv2 = *(const float4*)(hf + (size_t)src*DD + dB);
            b0 += hv2.x + ct[dB+0]; b1v += hv2.y + ct[dB+1];
            b2v += hv2.z + ct[dB+2]; b3 += hv2.w + ct[dB+3];
          }
        }
      }
    }
    ushort* ag = agg + (size_t)row*KA1;
    uint2 oA; oA.x = pk2(a0, a1); oA.y = pk2(a2, a3);
    *(uint2*)(ag + dA) = oA;
    if (laneB){
      uint2 oB;
      if (validB){ oB.x = pk2(b0, b1v); oB.y = pk2(b2v, b3); }
      else       { oB.x = 0; oB.y = 0; }
      *(uint2*)(ag + dB) = oB;
    }
  }
}

// ==== PERSISTENT GEMM1: m1 = relu(agg @ W1 + b1) ====
// 1280 blocks x 512 thr. Block: jcol = bid/256 (fixed 128-col W1T block,
// full K=320 resident in LDS, 80KB, octet-XOR swizzled), sub = bid%256;
// mtiles sub, sub+256, ... (3-4 per block). Continuous A-tile pipeline:
// 3-buf, 1 gload/thread/tile, WAITV(1) — never drains across mtiles.
// Epilogue per mtile: frags -> Bo bounce (stride 144: 16B-aligned reads,
// conflict-free writes) -> coalesced dwordx4 stores; WAITV(1) drains stores
// (in-order vmcnt retirement keeps the A-pipeline count exact).
__global__ __launch_bounds__(512) void gemm1_persist(
    const ushort* __restrict__ agg,     // [MPAD][KA1]
    const ushort* __restrict__ W1T_l,   // [640][320]
    const float* __restrict__ b1_l,     // [600]
    ushort* __restrict__ m1)            // [MPAD][608]
{
  __shared__ ushort Bw[128*KA1];   // 80 KB
  __shared__ ushort As[3][4096];   // 24 KB
  __shared__ ushort Bo[128*144];   // 36 KB bounce

  int tid = threadIdx.x;
  int lane = tid & 63, w = tid >> 6;
  int wm = (w >> 2) * 64;          // 0 / 64
  int wn = (w & 3) * 32;           // 0..96

  int nwg = gridDim.x;             // 1280 (q=160, r=0)
  int q = nwg >> 3;
  int xcd = blockIdx.x & 7, bix = blockIdx.x >> 3;
  int bid = xcd * q + bix;
  int jcol = bid >> 8;             // 0..4
  int sub  = bid & 255;            // 0..255
  int totMT = (sub < 14) ? 4 : 3;  // mtiles: sub + 256*t < 782

  int fr = lane & 15;
  int kq = lane >> 4;
  int ko8 = (kq ^ ((fr >> 1) & 3)) * 8;
  int cc = fr, cr = kq * 4;

  // ---- stage Bw once (reg -> swizzled ds_write) ----
  {
    const ushort* src = W1T_l + (size_t)jcol * 128 * KA1;
    #pragma unroll
    for (int rr = 0; rr < 10; ++rr){
      int L = rr * 512 + tid;          // 16B-chunk index, 0..5119
      int row = (L * 8) / KA1;
      int g   = ((L * 8) % KA1) >> 3;  // granule 0..39
      uint4 v = *(const uint4*)(src + (size_t)row * KA1 + g * 8);
      int ph = (g & ~7) | ((g & 7) ^ (row & 7));
      *(uint4*)&Bw[row * KA1 + ph * 8] = v;
    }
  }
  __syncthreads();   // one-time full drain: clean vmcnt slate

  // ---- continuous A pipeline ----
  int r0 = tid >> 2;                            // 0..127
  int kc = ((tid & 3) ^ ((tid >> 3) & 3)) * 8;
  const ushort* ApS = agg + ((size_t)sub * 128 + r0) * KA1 + kc;
  int smt = 0, skt = 0, sB = 0;
#define STAGE1() do { \
    __builtin_amdgcn_global_load_lds( \
        GLBP(ApS + (size_t)smt * (256u*128u*KA1) + skt * 32), \
        LDSP(&As[sB][w*512]), 16, 0, 0); \
    ++skt; if (skt == 10){ skt = 0; ++smt; } \
    ++sB; if (sB == 3) sB = 0; \
  } while (0)

  STAGE1(); STAGE1();              // (0,0)->buf0, (0,1)->buf1
  WAITV(1);
  __builtin_amdgcn_s_barrier();

  int totT = totMT * 10;
  int cur = 0;
  for (int mt = 0; mt < totMT; ++mt){
    int m0 = (sub + (mt << 8)) * 128;
    f32x4 acc[4][2] = {};
    for (int kt = 0; kt < 10; ++kt){
      int T = mt * 10 + kt;
      if (T + 2 < totT) STAGE1();
      short8 af[4], bw[2];
      #pragma unroll
      for (int i = 0; i < 4; ++i)
        af[i] = *(const short8*)&As[cur][(wm + i*16 + fr)*32 + ko8];
      int g = kt * 4 + kq;
      int ph = (g & ~7) | ((g & 7) ^ (fr & 7));
      #pragma unroll
      for (int j2 = 0; j2 < 2; ++j2)
        bw[j2] = *(const short8*)&Bw[(wn + j2*16 + fr)*KA1 + ph*8];
      #pragma unroll
      for (int i = 0; i < 4; ++i)
        #pragma unroll
        for (int j2 = 0; j2 < 2; ++j2)
          acc[i][j2] = __builtin_amdgcn_mfma_f32_16x16x32_bf16(af[i], bw[j2], acc[i][j2], 0, 0, 0);
      if (T + 1 < totT){
        if (T + 2 < totT) WAITV(1);
        else              WAITV(0);
        __builtin_amdgcn_s_barrier();
      }
      cur = cur + 1; if (cur == 3) cur = 0;
    }
    // ---- epilogue: bounce -> coalesced m1 stores ----
    #pragma unroll
    for (int i = 0; i < 4; ++i){
      #pragma unroll
      for (int j2 = 0; j2 < 2; ++j2){
        int col = wn + j2*16 + cc;
        int gcol = jcol*128 + col;
        float bv = (gcol < 2*DD) ? b1_l[gcol] : 0.0f;
        #pragma unroll
        for (int r2 = 0; r2 < 4; ++r2){
          int row = wm + i*16 + cr + r2;
          Bo[row*144 + col] = f2bf(fmaxf(acc[i][j2][r2] + bv, 0.0f));
        }
      }
    }
    asm volatile("s_waitcnt lgkmcnt(0)" ::: "memory");
    __builtin_amdgcn_sched_barrier(0);
    __builtin_amdgcn_s_barrier();
    {
      int row = tid >> 2, colb = (tid & 3) * 32;
      const uint4* bo = (const uint4*)&Bo[row*144 + colb];
      ushort* dst = m1 + (size_t)(m0 + row) * N1 + jcol*128 + colb;
      #pragma unroll
      for (int qd = 0; qd < 4; ++qd){
        int gcol = jcol*128 + colb + qd*8;
        if (gcol + 8 <= N1){
          uint4 v = bo[qd];
          *(uint4*)(dst + qd*8) = v;
        }
      }
    }
    WAITV(1);                       // drain stores; A-pipeline keeps 1 in flight
    __builtin_amdgcn_s_barrier();
  }
#undef STAGE1
}

// ---- GEMM2: 256x128 tile, 8 waves, 3-buf counted vmcnt (r6/r8-proven) ----
template<int OUT_BF16, int RELU, int STATS>
__global__ __launch_bounds__(512) void gemm_256(
    const ushort* __restrict__ A, int lda,
    const ushort* __restrict__ B, int ldb,
    void* __restrict__ Cp, int ldc,
    int kTiles, const float* __restrict__ bias, int biasN,
    int Mvalid, int Nvalid, int nColTiles, float* __restrict__ statf)
{
  __shared__ ushort As[3][8192];
  __shared__ ushort Bs[3][4096];
  int tid = threadIdx.x;
  int lane = tid & 63, w = tid >> 6;
  int wm = (w >> 1) * 64, wn = (w & 1) * 64;

  int nwg = gridDim.x;
  int q = nwg >> 3, r = nwg & 7;
  int xcd = blockIdx.x & 7, idx = blockIdx.x >> 3;
  int bid = (xcd < r ? xcd * (q + 1) : r * (q + 1) + (xcd - r) * q) + idx;
  int m0 = (bid / nColTiles) * 256;
  int n0 = (bid % nColTiles) * 128;

  int r0 = tid >> 2;
  int kc = ((tid & 3) ^ ((tid >> 3) & 3)) * 8;
  const ushort* Ap = A + (size_t)(m0 + r0)*lda + kc;
  const ushort* Bp = B + (size_t)(n0 + r0)*ldb + kc;

  f32x4 acc[4][4] = {};

#define STAGE(buf, kt) do { \
    int _ko = (kt) * 32; \
    __builtin_amdgcn_global_load_lds(GLBP(Ap + _ko),                   LDSP(&As[buf][w*512]),        16, 0, 0); \
    __builtin_amdgcn_global_load_lds(GLBP(Ap + _ko + (size_t)128*lda), LDSP(&As[buf][w*512 + 4096]), 16, 0, 0); \
    __builtin_amdgcn_global_load_lds(GLBP(Bp + _ko),                   LDSP(&Bs[buf][w*512]),        16, 0, 0); \
  } while (0)

  STAGE(0, 0);
  STAGE(1, 1);
  WAITV(3);
  __builtin_amdgcn_s_barrier();

  int fr = lane & 15;
  int ko8 = (((lane >> 4) ^ ((fr >> 1) & 3))) * 8;
  int cur = 0;
  for (int kt = 0; kt < kTiles; ++kt){
    int sb = cur + 2; if (sb >= 3) sb -= 3;
    if (kt + 2 < kTiles) STAGE(sb, kt + 2);
    short8 af[4], bfv[4];
    #pragma unroll
    for (int i = 0; i < 4; ++i)
      af[i] = *(const short8*)&As[cur][(wm + i*16 + fr)*32 + ko8];
    #pragma unroll
    for (int j = 0; j < 4; ++j)
      bfv[j] = *(const short8*)&Bs[cur][(wn + j*16 + fr)*32 + ko8];
    #pragma unroll
    for (int i = 0; i < 4; ++i)
      #pragma unroll
      for (int j = 0; j < 4; ++j)
        acc[i][j] = __builtin_amdgcn_mfma_f32_16x16x32_bf16(af[i], bfv[j], acc[i][j], 0, 0, 0);
    if (kt + 1 < kTiles){
      if (kt + 2 < kTiles) WAITV(3);
      else                 WAITV(0);
      __builtin_amdgcn_s_barrier();
    }
    cur = cur + 1; if (cur >= 3) cur = 0;
  }
#undef STAGE

  int cc = lane & 15, cr = (lane >> 4) * 4;
  float ps[4], pq[4];
  if (STATS){
    #pragma unroll
    for (int j = 0; j < 4; ++j){ ps[j] = 0.0f; pq[j] = 0.0f; }
  }
  #pragma unroll
  for (int i = 0; i < 4; ++i){
    #pragma unroll
    for (int j = 0; j < 4; ++j){
      int col = n0 + wn + j*16 + cc;
      if (col >= Nvalid) continue;
      float bv = (col < biasN) ? bias[col] : 0.0f;
      #pragma unroll
      for (int r2 = 0; r2 < 4; ++r2){
        int row = m0 + wm + i*16 + cr + r2;
        if (row < Mvalid){
          float v = acc[i][j][r2] + bv;
          if (RELU) v = fmaxf(v, 0.0f);
          if (OUT_BF16) ((ushort*)Cp)[(size_t)row*ldc + col] = f2bf(v);
          else          ((float*) Cp)[(size_t)row*ldc + col] = v;
          if (STATS){ ps[j] += v; pq[j] += v * v; }
        }
      }
    }
  }
  if (STATS){
    #pragma unroll
    for (int j = 0; j < 4; ++j){
      float s = ps[j], qv = pq[j];
      s += __shfl_xor(s, 16); qv += __shfl_xor(qv, 16);
      s += __shfl_xor(s, 32); qv += __shfl_xor(qv, 32);
      int col = n0 + wn + j*16 + cc;
      if ((lane >> 4) == 0 && col < Nvalid){
        unsafeAtomicAdd(&statf[col], s);
        unsafeAtomicAdd(&statf[N2T + col], qv);
      }
    }
  }
}

// ---------------- per-column scale/shift from stats ------------------------
__global__ void make_norm(const float* __restrict__ statf, const float* __restrict__ gamma,
                          const float* __restrict__ beta, float2* __restrict__ ss){
  int d = threadIdx.x;
  if (d >= DD) return;
  double mu = (double)statf[d] / (double)NN;
  double var = (double)statf[N2T + d] / (double)NN - mu * mu;
  float inv = rsqrtf((float)var + 1e-5f);
  float sc = inv * gamma[d];
  ss[d] = make_float2(sc, beta[d] - (float)mu * sc);
}

// ---------------- final norm (no relu) -> d_out ----------------------------
__global__ void apply_norm(const float* __restrict__ m2, const float2* __restrict__ ss,
                           float* __restrict__ out){
  int row = blockIdx.x;
  int d = threadIdx.x;
  if (d >= DD) return;
  float2 s = ss[d];
  out[(size_t)row*DD + d] = m2[(size_t)row*DD + d] * s.x + s.y;
}

extern "C" void kernel_launch(void* const* d_in, const int* in_sizes, int n_in,
                              void* d_out, int out_size, void* d_ws, size_t ws_size,
                              hipStream_t stream) {
  const float* x     = (const float*)d_in[0];
  const int*   ei    = (const int*)  d_in[1];
  const int*   ea    = (const int*)  d_in[2];
  const float* W1    = (const float*)d_in[3];
  const float* b1    = (const float*)d_in[4];
  const float* W2    = (const float*)d_in[5];
  const float* b2    = (const float*)d_in[6];
  const float* E1    = (const float*)d_in[7];
  const float* E2    = (const float*)d_in[8];
  const float* gamma = (const float*)d_in[9];
  const float* beta  = (const float*)d_in[10];

  char* p = (char*)d_ws;
  float*  m2buf = (float*) p; p += (size_t)NN * DD * 4;
  ushort* m2bf  = (ushort*)p; p += (size_t)NN * DDB * 2;
  ushort* agg   = (ushort*)p; p += (size_t)MPAD * KA1 * 2;
  ushort* m1    = (ushort*)p; p += (size_t)MPAD * N1 * 2;
  ushort* W1T   = (ushort*)p; p += (size_t)NL * N1T * KA1 * 2;
  ushort* W2T   = (ushort*)p; p += (size_t)NL * N2T * K2 * 2;
  float*  ctab  = (float*) p; p += (size_t)NL * NCMB * DDB * 4;
  int*    deg   = (int*)   p; p += (size_t)NN * 4;
  int*    rs    = (int*)   p; p += (size_t)(NN + 16) * 4;
  int*    bsum  = (int*)   p; p += (size_t)512 * 4;
  int*    cursor= (int*)   p; p += (size_t)NN * 4;
  int*    edges = (int*)   p; p += (size_t)NE * 4;
  float*  statf = (float*) p; p += (size_t)2 * N2T * 4;
  float2* ss    = (float2*)p;

  {
    int total = NL*N1T*KA1 + NL*N2T*K2;
    prep_weights<<<(total + 255)/256, 256, 0, stream>>>(W1, W2, W1T, W2T);
    int tc = NL * NCMB * DDB;
    prep_ctab<<<(tc + 255)/256, 256, 0, stream>>>(E1, E2, ctab);
  }
  hipMemsetAsync(deg, 0, (size_t)NN*4, stream);
  hipMemsetAsync(cursor, 0, (size_t)NN*4, stream);
  csr_count<<<(NE + 255)/256, 256, 0, stream>>>(ei, deg);
  scan_blk<<<NBLK, 256, 0, stream>>>(deg, rs, bsum);
  scan_top<<<1, 512, 0, stream>>>(bsum);
  scan_add<<<NBLK, 256, 0, stream>>>(rs, bsum);
  csr_fill<<<(NE + 255)/256, 256, 0, stream>>>(ei, ea, rs, cursor, edges);

  for (int l = 0; l < NL; ++l){
    const float* ctab_l = ctab + (size_t)l * NCMB * DDB;

    if (l == 0)
      gather_agg<0><<<1024, 256, 0, stream>>>(x, nullptr, ctab_l, rs, edges, agg);
    else
      gather_agg<1><<<1024, 256, 0, stream>>>(m2bf, ss, ctab_l, rs, edges, agg);

    // m1 = relu(agg @ W1 + b1): persistent, W1-block LDS-resident
    gemm1_persist<<<1280, 512, 0, stream>>>(
        agg, W1T + (size_t)l*N1T*KA1, b1 + (size_t)l*2*DD, m1);

    hipMemsetAsync(statf, 0, (size_t)2*N2T*4, stream);

    // m2 = m1 @ W2 + b2 (+ fused stats)
    if (l < NL - 1)
      gemm_256<1,0,1><<<(MPAD/256) * (N2T/128), 512, 0, stream>>>(
          m1, N1, W2T + (size_t)l*N2T*K2, K2, m2bf, DDB, K2/32,
          b2 + (size_t)l*DD, DD, NN, DD, N2T/128, statf);
    else
      gemm_256<0,0,1><<<(MPAD/256) * (N2T/128), 512, 0, stream>>>(
          m1, N1, W2T + (size_t)l*N2T*K2, K2, m2buf, DD, K2/32,
          b2 + (size_t)l*DD, DD, NN, DD, N2T/128, statf);

    make_norm<<<1, 320, 0, stream>>>(statf, gamma + (size_t)l*DD, beta + (size_t)l*DD, ss);
  }
  apply_norm<<<NN, 320, 0, stream>>>(m2buf, ss, (float*)d_out);
}

// Round 12
// 1522.535 us; speedup vs baseline: 1.1257x; 1.1257x over previous
//
#include <hip/hip_runtime.h>
#include <hip/hip_bf16.h>

#define NN 100000
#define NE 250000
#define DD 300
#define DDB 304       // bf16 h row stride
#define NL 5
#define MPAD 100096   // 782*128 == 8*12512
#define KA1 320       // padded K for GEMM1
#define N1 608        // m1 width, K of GEMM2
#define N1T 640       // W1T rows
#define K2 608
#define N2T 384       // W2T rows
#define NBLK 391
#define NCMB 19
#define XCHUNK 12512  // MPAD/8: rows per XCD for gather->G1 L2 alignment

typedef __attribute__((ext_vector_type(8))) short short8;
typedef __attribute__((ext_vector_type(4))) float f32x4;

#define GLBP(x) ((const __attribute__((address_space(1))) unsigned int*)(x))
#define LDSP(x) ((__attribute__((address_space(3))) unsigned int*)(x))
#define WAITV(N) asm volatile("s_waitcnt vmcnt(" #N ")" ::: "memory")

__device__ __forceinline__ ushort f2bf(float f){
  unsigned u = __float_as_uint(f);
  u += 0x7FFFu + ((u >> 16) & 1u);
  return (ushort)(u >> 16);
}
__device__ __forceinline__ float bf2f(ushort h){
  return __uint_as_float((unsigned)h << 16);
}
__device__ __forceinline__ unsigned pk2(float a, float b){
  return (unsigned)f2bf(a) | ((unsigned)f2bf(b) << 16);
}

// ---------------- weight prep: transpose + f32->bf16, zero-padded ----------
__global__ void prep_weights(const float* __restrict__ W1, const float* __restrict__ W2,
                             ushort* __restrict__ W1T, ushort* __restrict__ W2T){
  int idx = blockIdx.x * 256 + threadIdx.x;
  const int total1 = NL * N1T * KA1;
  const int total2 = NL * N2T * K2;
  if (idx < total1){
    int l = idx / (N1T * KA1);
    int rem = idx % (N1T * KA1);
    int n = rem / KA1, k = rem % KA1;
    float v = (n < 2*DD && k < DD) ? W1[(size_t)l*DD*2*DD + (size_t)k*2*DD + n] : 0.0f;
    W1T[idx] = f2bf(v);
  } else {
    int idx2 = idx - total1;
    if (idx2 < total2){
      int l = idx2 / (N2T * K2);
      int rem = idx2 % (N2T * K2);
      int n = rem / K2, k = rem % K2;
      float v = (n < DD && k < 2*DD) ? W2[(size_t)l*2*DD*DD + (size_t)k*DD + n] : 0.0f;
      W2T[idx2] = f2bf(v);
    }
  }
}

// -------- combo tables ----------
__global__ void prep_ctab(const float* __restrict__ E1, const float* __restrict__ E2,
                          float* __restrict__ ctab){
  int idx = blockIdx.x * 256 + threadIdx.x;
  if (idx >= NL * NCMB * DDB) return;
  int l = idx / (NCMB * DDB);
  int rem = idx % (NCMB * DDB);
  int c = rem / DDB, d = rem % DDB;
  float v = 0.0f;
  if (d < DD){
    int bt = (c < 18) ? (c / 3) : 4;
    int bd = (c < 18) ? (c % 3) : 0;
    v = E1[(size_t)l*6*DD + bt*DD + d] + E2[(size_t)l*3*DD + bd*DD + d];
  }
  ctab[idx] = v;
}

// ---------------- CSR build ------------------------------------------------
__global__ void csr_count(const int* __restrict__ ei, int* __restrict__ deg){
  int e = blockIdx.x * 256 + threadIdx.x;
  if (e < NE) atomicAdd(&deg[ei[NE + e]], 1);
}

__global__ void scan_blk(const int* __restrict__ deg, int* __restrict__ rs, int* __restrict__ bsum){
  __shared__ int tmp[256];
  int i = blockIdx.x * 256 + threadIdx.x;
  int v = (i < NN) ? deg[i] : 0;
  tmp[threadIdx.x] = v;
  __syncthreads();
  #pragma unroll
  for (int off = 1; off < 256; off <<= 1){
    int t = (threadIdx.x >= off) ? tmp[threadIdx.x - off] : 0;
    __syncthreads();
    tmp[threadIdx.x] += t;
    __syncthreads();
  }
  if (i < NN) rs[i] = tmp[threadIdx.x] - v;
  if (threadIdx.x == 255) bsum[blockIdx.x] = tmp[255];
}

__global__ void scan_top(int* __restrict__ bsum){
  __shared__ int tmp[512];
  int v = (threadIdx.x < NBLK) ? bsum[threadIdx.x] : 0;
  tmp[threadIdx.x] = v;
  __syncthreads();
  #pragma unroll
  for (int off = 1; off < 512; off <<= 1){
    int t = (threadIdx.x >= off) ? tmp[threadIdx.x - off] : 0;
    __syncthreads();
    tmp[threadIdx.x] += t;
    __syncthreads();
  }
  if (threadIdx.x < NBLK) bsum[threadIdx.x] = tmp[threadIdx.x] - v;
}

__global__ void scan_add(int* __restrict__ rs, const int* __restrict__ bsum){
  int i = blockIdx.x * 256 + threadIdx.x;
  if (i < NN) rs[i] += bsum[blockIdx.x];
  if (i == 0) rs[NN] = NE;
}

__global__ void csr_fill(const int* __restrict__ ei, const int* __restrict__ ea,
                         const int* __restrict__ rs, int* __restrict__ cursor,
                         int* __restrict__ edges){
  int e = blockIdx.x * 256 + threadIdx.x;
  if (e < NE){
    int dst = ei[NE + e];
    int src = ei[e];
    int c = ea[2*e] * 3 + ea[2*e + 1];
    int p = rs[dst] + atomicAdd(&cursor[dst], 1);
    edges[p] = src | (c << 20);
  }
}

// ---- gather: wave-per-row, XCD-CHUNKED rows so agg writes land on the same
// ---- XCD L2 that G1's 256-tile swizzle reads (rows [x*12512,(x+1)*12512)).
template<int HBF>
__global__ __launch_bounds__(256) void gather_agg(
    const void* __restrict__ hp, const float2* __restrict__ ss,
    const float* __restrict__ ctab_l,
    const int* __restrict__ rs, const int* __restrict__ edges,
    ushort* __restrict__ agg)
{
  int lane = threadIdx.x & 63;
  int wq = __builtin_amdgcn_readfirstlane(threadIdx.x >> 6);
  int xcd  = blockIdx.x & 7;                 // same assumption as gemm swizzle
  int widx = (blockIdx.x >> 3) * 4 + wq;     // 0..511 within XCD (1024 blocks)
  int rbeg = xcd * XCHUNK + widx;
  int rend = (xcd + 1) * XCHUNK;
  int dA = lane * 4;
  int dB = 256 + lane * 4;
  bool laneB  = (lane < 16);
  bool validB = (dB < DD);

  float scA[4], shA[4], scB[4], shB[4];
  if (HBF){
    #pragma unroll
    for (int j = 0; j < 4; ++j){
      float2 s = ss[dA + j]; scA[j] = s.x; shA[j] = s.y;
    }
    if (validB){
      #pragma unroll
      for (int j = 0; j < 4; ++j){
        float2 s = ss[dB + j]; scB[j] = s.x; shB[j] = s.y;
      }
    }
  }

  const float*  hf = (const float*)hp;
  const ushort* hb = (const ushort*)hp;
  const float* ctS = ctab_l + 18*DDB;

  for (int row = rbeg; row < rend; row += 512){
    float a0=0,a1=0,a2=0,a3=0, b0=0,b1v=0,b2v=0,b3=0;
    if (row < NN){
      if (HBF){
        uint2 hw = *(const uint2*)(hb + (size_t)row*DDB + dA);
        a0 = fmaxf(bf2f((ushort)hw.x)*scA[0]+shA[0],0.f)      + ctS[dA+0];
        a1 = fmaxf(bf2f((ushort)(hw.x>>16))*scA[1]+shA[1],0.f)+ ctS[dA+1];
        a2 = fmaxf(bf2f((ushort)hw.y)*scA[2]+shA[2],0.f)      + ctS[dA+2];
        a3 = fmaxf(bf2f((ushort)(hw.y>>16))*scA[3]+shA[3],0.f)+ ctS[dA+3];
        if (validB){
          uint2 hv = *(const uint2*)(hb + (size_t)row*DDB + dB);
          b0  = fmaxf(bf2f((ushort)hv.x)*scB[0]+shB[0],0.f)      + ctS[dB+0];
          b1v = fmaxf(bf2f((ushort)(hv.x>>16))*scB[1]+shB[1],0.f)+ ctS[dB+1];
          b2v = fmaxf(bf2f((ushort)hv.y)*scB[2]+shB[2],0.f)      + ctS[dB+2];
          b3  = fmaxf(bf2f((ushort)(hv.y>>16))*scB[3]+shB[3],0.f)+ ctS[dB+3];
        }
      } else {
        float4 hv = *(const float4*)(hf + (size_t)row*DD + dA);
        a0 = hv.x + ctS[dA+0]; a1 = hv.y + ctS[dA+1];
        a2 = hv.z + ctS[dA+2]; a3 = hv.w + ctS[dA+3];
        if (validB){
          float4 hv2 = *(const float4*)(hf + (size_t)row*DD + dB);
          b0 = hv2.x + ctS[dB+0]; b1v = hv2.y + ctS[dB+1];
          b2v = hv2.z + ctS[dB+2]; b3 = hv2.w + ctS[dB+3];
        }
      }
      int p = rs[row], pe = rs[row + 1];
      for (; p < pe; ++p){
        int ew = edges[p];
        int src = ew & 0xFFFFF;
        const float* ct = ctab_l + (ew >> 20)*DDB;
        if (HBF){
          uint2 hw = *(const uint2*)(hb + (size_t)src*DDB + dA);
          a0 += fmaxf(bf2f((ushort)hw.x)*scA[0]+shA[0],0.f)      + ct[dA+0];
          a1 += fmaxf(bf2f((ushort)(hw.x>>16))*scA[1]+shA[1],0.f)+ ct[dA+1];
          a2 += fmaxf(bf2f((ushort)hw.y)*scA[2]+shA[2],0.f)      + ct[dA+2];
          a3 += fmaxf(bf2f((ushort)(hw.y>>16))*scA[3]+shA[3],0.f)+ ct[dA+3];
          if (validB){
            uint2 hv = *(const uint2*)(hb + (size_t)src*DDB + dB);
            b0  += fmaxf(bf2f((ushort)hv.x)*scB[0]+shB[0],0.f)      + ct[dB+0];
            b1v += fmaxf(bf2f((ushort)(hv.x>>16))*scB[1]+shB[1],0.f)+ ct[dB+1];
            b2v += fmaxf(bf2f((ushort)hv.y)*scB[2]+shB[2],0.f)      + ct[dB+2];
            b3  += fmaxf(bf2f((ushort)(hv.y>>16))*scB[3]+shB[3],0.f)+ ct[dB+3];
          }
        } else {
          float4 hv = *(const float4*)(hf + (size_t)src*DD + dA);
          a0 += hv.x + ct[dA+0]; a1 += hv.y + ct[dA+1];
          a2 += hv.z + ct[dA+2]; a3 += hv.w + ct[dA+3];
          if (validB){
            float4 hv2 = *(const float4*)(hf + (size_t)src*DD + dB);
            b0 += hv2.x + ct[dB+0]; b1v += hv2.y + ct[dB+1];
            b2v += hv2.z + ct[dB+2]; b3 += hv2.w + ct[dB+3];
          }
        }
      }
    }
    ushort* ag = agg + (size_t)row*KA1;
    uint2 oA; oA.x = pk2(a0, a1); oA.y = pk2(a2, a3);
    *(uint2*)(ag + dA) = oA;
    if (laneB){
      uint2 oB;
      if (validB){ oB.x = pk2(b0, b1v); oB.y = pk2(b2v, b3); }
      else       { oB.x = 0; oB.y = 0; }
      *(uint2*)(ag + dB) = oB;
    }
  }
}

// ---- GEMM: 256x128 tile, 8 waves, 3-buf counted vmcnt (r6-proven best) ----
template<int OUT_BF16, int RELU, int STATS>
__global__ __launch_bounds__(512) void gemm_256(
    const ushort* __restrict__ A, int lda,
    const ushort* __restrict__ B, int ldb,
    void* __restrict__ Cp, int ldc,
    int kTiles, const float* __restrict__ bias, int biasN,
    int Mvalid, int Nvalid, int nColTiles, float* __restrict__ statf)
{
  __shared__ ushort As[3][8192];
  __shared__ ushort Bs[3][4096];
  int tid = threadIdx.x;
  int lane = tid & 63, w = tid >> 6;
  int wm = (w >> 1) * 64, wn = (w & 1) * 64;

  int nwg = gridDim.x;
  int q = nwg >> 3, r = nwg & 7;
  int xcd = blockIdx.x & 7, idx = blockIdx.x >> 3;
  int bid = (xcd < r ? xcd * (q + 1) : r * (q + 1) + (xcd - r) * q) + idx;
  int m0 = (bid / nColTiles) * 256;
  int n0 = (bid % nColTiles) * 128;

  int r0 = tid >> 2;
  int kc = ((tid & 3) ^ ((tid >> 3) & 3)) * 8;
  const ushort* Ap = A + (size_t)(m0 + r0)*lda + kc;
  const ushort* Bp = B + (size_t)(n0 + r0)*ldb + kc;

  f32x4 acc[4][4] = {};

#define STAGE(buf, kt) do { \
    int _ko = (kt) * 32; \
    __builtin_amdgcn_global_load_lds(GLBP(Ap + _ko),                   LDSP(&As[buf][w*512]),        16, 0, 0); \
    __builtin_amdgcn_global_load_lds(GLBP(Ap + _ko + (size_t)128*lda), LDSP(&As[buf][w*512 + 4096]), 16, 0, 0); \
    __builtin_amdgcn_global_load_lds(GLBP(Bp + _ko),                   LDSP(&Bs[buf][w*512]),        16, 0, 0); \
  } while (0)

  STAGE(0, 0);
  STAGE(1, 1);
  WAITV(3);
  __builtin_amdgcn_s_barrier();

  int fr = lane & 15;
  int ko8 = (((lane >> 4) ^ ((fr >> 1) & 3))) * 8;
  int cur = 0;
  for (int kt = 0; kt < kTiles; ++kt){
    int sb = cur + 2; if (sb >= 3) sb -= 3;
    if (kt + 2 < kTiles) STAGE(sb, kt + 2);
    short8 af[4], bfv[4];
    #pragma unroll
    for (int i = 0; i < 4; ++i)
      af[i] = *(const short8*)&As[cur][(wm + i*16 + fr)*32 + ko8];
    #pragma unroll
    for (int j = 0; j < 4; ++j)
      bfv[j] = *(const short8*)&Bs[cur][(wn + j*16 + fr)*32 + ko8];
    #pragma unroll
    for (int i = 0; i < 4; ++i)
      #pragma unroll
      for (int j = 0; j < 4; ++j)
        acc[i][j] = __builtin_amdgcn_mfma_f32_16x16x32_bf16(af[i], bfv[j], acc[i][j], 0, 0, 0);
    if (kt + 1 < kTiles){
      if (kt + 2 < kTiles) WAITV(3);
      else                 WAITV(0);
      __builtin_amdgcn_s_barrier();
    }
    cur = cur + 1; if (cur >= 3) cur = 0;
  }
#undef STAGE

  int cc = lane & 15, cr = (lane >> 4) * 4;
  float ps[4], pq[4];
  if (STATS){
    #pragma unroll
    for (int j = 0; j < 4; ++j){ ps[j] = 0.0f; pq[j] = 0.0f; }
  }
  #pragma unroll
  for (int i = 0; i < 4; ++i){
    #pragma unroll
    for (int j = 0; j < 4; ++j){
      int col = n0 + wn + j*16 + cc;
      if (col >= Nvalid) continue;
      float bv = (col < biasN) ? bias[col] : 0.0f;
      #pragma unroll
      for (int r2 = 0; r2 < 4; ++r2){
        int row = m0 + wm + i*16 + cr + r2;
        if (row < Mvalid){
          float v = acc[i][j][r2] + bv;
          if (RELU) v = fmaxf(v, 0.0f);
          if (OUT_BF16) ((ushort*)Cp)[(size_t)row*ldc + col] = f2bf(v);
          else          ((float*) Cp)[(size_t)row*ldc + col] = v;
          if (STATS){ ps[j] += v; pq[j] += v * v; }
        }
      }
    }
  }
  if (STATS){
    #pragma unroll
    for (int j = 0; j < 4; ++j){
      float s = ps[j], qv = pq[j];
      s += __shfl_xor(s, 16); qv += __shfl_xor(qv, 16);
      s += __shfl_xor(s, 32); qv += __shfl_xor(qv, 32);
      int col = n0 + wn + j*16 + cc;
      if ((lane >> 4) == 0 && col < Nvalid){
        unsafeAtomicAdd(&statf[col], s);
        unsafeAtomicAdd(&statf[N2T + col], qv);
      }
    }
  }
}

// ---------------- per-column scale/shift from stats ------------------------
__global__ void make_norm(const float* __restrict__ statf, const float* __restrict__ gamma,
                          const float* __restrict__ beta, float2* __restrict__ ss){
  int d = threadIdx.x;
  if (d >= DD) return;
  double mu = (double)statf[d] / (double)NN;
  double var = (double)statf[N2T + d] / (double)NN - mu * mu;
  float inv = rsqrtf((float)var + 1e-5f);
  float sc = inv * gamma[d];
  ss[d] = make_float2(sc, beta[d] - (float)mu * sc);
}

// ---------------- final norm (no relu) -> d_out ----------------------------
__global__ void apply_norm(const float* __restrict__ m2, const float2* __restrict__ ss,
                           float* __restrict__ out){
  int row = blockIdx.x;
  int d = threadIdx.x;
  if (d >= DD) return;
  float2 s = ss[d];
  out[(size_t)row*DD + d] = m2[(size_t)row*DD + d] * s.x + s.y;
}

extern "C" void kernel_launch(void* const* d_in, const int* in_sizes, int n_in,
                              void* d_out, int out_size, void* d_ws, size_t ws_size,
                              hipStream_t stream) {
  const float* x     = (const float*)d_in[0];
  const int*   ei    = (const int*)  d_in[1];
  const int*   ea    = (const int*)  d_in[2];
  const float* W1    = (const float*)d_in[3];
  const float* b1    = (const float*)d_in[4];
  const float* W2    = (const float*)d_in[5];
  const float* b2    = (const float*)d_in[6];
  const float* E1    = (const float*)d_in[7];
  const float* E2    = (const float*)d_in[8];
  const float* gamma = (const float*)d_in[9];
  const float* beta  = (const float*)d_in[10];

  char* p = (char*)d_ws;
  float*  m2buf = (float*) p; p += (size_t)NN * DD * 4;
  ushort* m2bf  = (ushort*)p; p += (size_t)NN * DDB * 2;
  ushort* agg   = (ushort*)p; p += (size_t)MPAD * KA1 * 2;
  ushort* m1    = (ushort*)p; p += (size_t)MPAD * N1 * 2;
  ushort* W1T   = (ushort*)p; p += (size_t)NL * N1T * KA1 * 2;
  ushort* W2T   = (ushort*)p; p += (size_t)NL * N2T * K2 * 2;
  float*  ctab  = (float*) p; p += (size_t)NL * NCMB * DDB * 4;
  int*    deg   = (int*)   p; p += (size_t)NN * 4;
  int*    rs    = (int*)   p; p += (size_t)(NN + 16) * 4;
  int*    bsum  = (int*)   p; p += (size_t)512 * 4;
  int*    cursor= (int*)   p; p += (size_t)NN * 4;
  int*    edges = (int*)   p; p += (size_t)NE * 4;
  float*  statf = (float*) p; p += (size_t)2 * N2T * 4;
  float2* ss    = (float2*)p;

  {
    int total = NL*N1T*KA1 + NL*N2T*K2;
    prep_weights<<<(total + 255)/256, 256, 0, stream>>>(W1, W2, W1T, W2T);
    int tc = NL * NCMB * DDB;
    prep_ctab<<<(tc + 255)/256, 256, 0, stream>>>(E1, E2, ctab);
  }
  hipMemsetAsync(deg, 0, (size_t)NN*4, stream);
  hipMemsetAsync(cursor, 0, (size_t)NN*4, stream);
  csr_count<<<(NE + 255)/256, 256, 0, stream>>>(ei, deg);
  scan_blk<<<NBLK, 256, 0, stream>>>(deg, rs, bsum);
  scan_top<<<1, 512, 0, stream>>>(bsum);
  scan_add<<<NBLK, 256, 0, stream>>>(rs, bsum);
  csr_fill<<<(NE + 255)/256, 256, 0, stream>>>(ei, ea, rs, cursor, edges);

  for (int l = 0; l < NL; ++l){
    const float* ctab_l = ctab + (size_t)l * NCMB * DDB;

    if (l == 0)
      gather_agg<0><<<1024, 256, 0, stream>>>(x, nullptr, ctab_l, rs, edges, agg);
    else
      gather_agg<1><<<1024, 256, 0, stream>>>(m2bf, ss, ctab_l, rs, edges, agg);

    // m1 = relu(agg @ W1 + b1): 256-tile d2 (r6-proven)
    gemm_256<1,1,0><<<(MPAD/256) * (N1T/128), 512, 0, stream>>>(
        agg, KA1, W1T + (size_t)l*N1T*KA1, KA1, m1, N1, KA1/32,
        b1 + (size_t)l*2*DD, 2*DD, MPAD, N1, N1T/128, nullptr);

    hipMemsetAsync(statf, 0, (size_t)2*N2T*4, stream);

    // m2 = m1 @ W2 + b2 (+ fused stats)
    if (l < NL - 1)
      gemm_256<1,0,1><<<(MPAD/256) * (N2T/128), 512, 0, stream>>>(
          m1, N1, W2T + (size_t)l*N2T*K2, K2, m2bf, DDB, K2/32,
          b2 + (size_t)l*DD, DD, NN, DD, N2T/128, statf);
    else
      gemm_256<0,0,1><<<(MPAD/256) * (N2T/128), 512, 0, stream>>>(
          m1, N1, W2T + (size_t)l*N2T*K2, K2, m2buf, DD, K2/32,
          b2 + (size_t)l*DD, DD, NN, DD, N2T/128, statf);

    make_norm<<<1, 320, 0, stream>>>(statf, gamma + (size_t)l*DD, beta + (size_t)l*DD, ss);
  }
  apply_norm<<<NN, 320, 0, stream>>>(m2buf, ss, (float*)d_out);
}